// Round 2
// baseline (3853.211 us; speedup 1.0000x reference)
//
#include <hip/hip_runtime.h>
#include <hip/hip_bf16.h>
#include <math.h>

#define NN 50000
#define EE 800000
#define GG 128
#define LGD 16

typedef unsigned int u32;
typedef __hip_bfloat16 bf16;

__device__ __forceinline__ float bflo(u32 u){ union{u32 x; float f;} c; c.x = u << 16; return c.f; }
__device__ __forceinline__ float bfhi(u32 u){ union{u32 x; float f;} c; c.x = u & 0xffff0000u; return c.f; }
__device__ __forceinline__ u32 f2bf(float f){
    union{float f; u32 u;} c; c.f = f;
    return (c.u + 0x7fffu + ((c.u >> 16) & 1u)) >> 16;  // RNE
}
__device__ __forceinline__ float siluf(float x){ return x / (1.f + expf(-x)); }
__device__ __forceinline__ float sigmf(float x){ return 1.f / (1.f + expf(-x)); }

// ---- dtype-polymorphic load/store: F32 ? float32 : bf16 -------------------
template<bool F32>
__device__ __forceinline__ float ld1(const void* p, size_t i){
    if (F32) return reinterpret_cast<const float*>(p)[i];
    return __bfloat162float(reinterpret_cast<const bf16*>(p)[i]);
}
template<bool F32>
__device__ __forceinline__ void ld8v(const void* p, size_t i, float* o){
    if (F32){
        const float4* q = reinterpret_cast<const float4*>(reinterpret_cast<const float*>(p) + i);
        float4 a = q[0], b = q[1];
        o[0]=a.x;o[1]=a.y;o[2]=a.z;o[3]=a.w;o[4]=b.x;o[5]=b.y;o[6]=b.z;o[7]=b.w;
    } else {
        uint4 q = *reinterpret_cast<const uint4*>(reinterpret_cast<const bf16*>(p) + i);
        o[0]=bflo(q.x);o[1]=bfhi(q.x);o[2]=bflo(q.y);o[3]=bfhi(q.y);
        o[4]=bflo(q.z);o[5]=bfhi(q.z);o[6]=bflo(q.w);o[7]=bfhi(q.w);
    }
}
template<bool F32>
__device__ __forceinline__ void st8v(void* p, size_t i, const float* f){
    if (F32){
        float4* q = reinterpret_cast<float4*>(reinterpret_cast<float*>(p) + i);
        q[0] = make_float4(f[0],f[1],f[2],f[3]);
        q[1] = make_float4(f[4],f[5],f[6],f[7]);
    } else {
        uint4 q;
        q.x = f2bf(f[0]) | (f2bf(f[1])<<16);
        q.y = f2bf(f[2]) | (f2bf(f[3])<<16);
        q.z = f2bf(f[4]) | (f2bf(f[5])<<16);
        q.w = f2bf(f[6]) | (f2bf(f[7])<<16);
        *reinterpret_cast<uint4*>(reinterpret_cast<bf16*>(p) + i) = q;
    }
}
template<bool F32>
__device__ __forceinline__ void ld2v(const void* p, size_t i, float& a, float& b){
    if (F32){ float2 q = *reinterpret_cast<const float2*>(reinterpret_cast<const float*>(p)+i); a=q.x; b=q.y; }
    else { u32 r = *reinterpret_cast<const u32*>(reinterpret_cast<const bf16*>(p)+i); a=bflo(r); b=bfhi(r); }
}
template<bool F32>
__device__ __forceinline__ void st2v(void* p, size_t i, float a, float b){
    if (F32){ *reinterpret_cast<float2*>(reinterpret_cast<float*>(p)+i) = make_float2(a,b); }
    else { *reinterpret_cast<u32*>(reinterpret_cast<bf16*>(p)+i) = f2bf(a) | (f2bf(b)<<16); }
}

// ---- dtype detector --------------------------------------------------------
__global__ __launch_bounds__(1024) void k_detect(const u32* __restrict__ q, int* __restrict__ flag){
    __shared__ int s;
    if (threadIdx.x == 0) s = 0;
    __syncthreads();
    int h = 0;
    #pragma unroll
    for (int i = 0; i < 4; i++){
        u32 w = q[threadIdx.x + i*1024];
        if ((w & 0x7F80u) == 0x7F80u) h = 1;
    }
    if (h) atomicOr(&s, 1);
    __syncthreads();
    if (threadIdx.x == 0) flag[0] = s;   // 1 = float32, 0 = bf16
}

// ---------------- CSR build (dtype-independent) ----------------------------
__global__ __launch_bounds__(256) void k_hist(const int* __restrict__ dst, int* __restrict__ cnt){
    const int e = blockIdx.x * 256 + threadIdx.x;
    atomicAdd(&cnt[dst[e]], 1);
}

__global__ __launch_bounds__(256) void k_scan(int* __restrict__ cur, int* __restrict__ off){
    const int S = 196;                // 256*196 = 50176 >= NN
    const int t = threadIdx.x;
    const int b0 = t * S;
    int lsum = 0;
    for (int k = 0; k < S; k++){
        int i = b0 + k;
        if (i < NN) lsum += cur[i];
    }
    __shared__ int ssum[256];
    ssum[t] = lsum;
    __syncthreads();
    #pragma unroll
    for (int d = 1; d < 256; d <<= 1){
        int tv = (t >= d) ? ssum[t - d] : 0;
        __syncthreads();
        ssum[t] += tv;
        __syncthreads();
    }
    int run = ssum[t] - lsum;         // exclusive strip offset
    for (int k = 0; k < S; k++){
        int i = b0 + k;
        if (i >= NN) break;
        int c = cur[i];
        off[i] = run;
        cur[i] = run;
        run += c;
    }
    if (t == 255) off[NN] = run;      // = EE
}

__global__ __launch_bounds__(256) void k_fill(const int* __restrict__ dst, int* __restrict__ cur,
                                              int* __restrict__ eidx){
    const int e = blockIdx.x * 256 + threadIdx.x;
    const int p = atomicAdd(&cur[dst[e]], 1);
    eidx[p] = e;
}

// ---------------- Kernel 1: node input projections -------------------------
template<bool F32>
__global__ __launch_bounds__(256) void k_node_pre(
    const int* __restrict__ mode,
    const void* __restrict__ node_s, const void* __restrict__ node_v,
    const void* __restrict__ Wns, const void* __restrict__ bns, const void* __restrict__ Wnv,
    float* __restrict__ ns, float* __restrict__ nv, float* __restrict__ nvn)
{
    if ((mode[0] != 0) != F32) return;
    __shared__ float sWns[GG*LGD];
    __shared__ float sWnv[GG*LGD];
    __shared__ float sb[LGD];
    __shared__ float sbuf[4][512];
    const int tid = threadIdx.x;
    for (int i = tid; i < GG*LGD; i += 256){
        sWns[i] = ld1<F32>(Wns, i);
        sWnv[i] = ld1<F32>(Wnv, i);
    }
    if (tid < LGD) sb[tid] = ld1<F32>(bns, tid);
    __syncthreads();

    const int w = tid >> 6, lane = tid & 63, c = lane & 15;
    const int n = blockIdx.x * 4 + w;        // NN = 12500*4
    {
        float tmp[8];
        if (lane < 16){
            ld8v<F32>(node_s, (size_t)n*GG + lane*8, tmp);
            float4* dp = reinterpret_cast<float4*>(&sbuf[w][lane*8]);
            dp[0] = make_float4(tmp[0],tmp[1],tmp[2],tmp[3]);
            dp[1] = make_float4(tmp[4],tmp[5],tmp[6],tmp[7]);
        } else {
            ld8v<F32>(node_v, (size_t)n*384 + (lane-16)*8, tmp);
            float4* dp = reinterpret_cast<float4*>(&sbuf[w][128 + (lane-16)*8]);
            dp[0] = make_float4(tmp[0],tmp[1],tmp[2],tmp[3]);
            dp[1] = make_float4(tmp[4],tmp[5],tmp[6],tmp[7]);
        }
    }
    __syncthreads();

    float acc;
    if (lane < 16){
        acc = sb[c];
        #pragma unroll 16
        for (int k = 0; k < GG; k++) acc += sbuf[w][k] * sWns[k*LGD + c];
    } else {
        const int v = (lane >> 4) - 1;
        const float* vb = &sbuf[w][128 + v*128];
        acc = 0.f;
        #pragma unroll 16
        for (int k = 0; k < GG; k++) acc += vb[k] * sWnv[k*LGD + c];
    }
    float v1 = __shfl(acc, 16 + c, 64);
    float v2 = __shfl(acc, 32 + c, 64);
    float v3 = __shfl(acc, 48 + c, 64);
    if (lane < 16){
        ns [(size_t)n*16 + c] = siluf(acc);
        nvn[(size_t)n*16 + c] = sqrtf(v1*v1 + v2*v2 + v3*v3 + 1e-12f);
    } else {
        nv[(size_t)n*48 + (lane - 16)] = acc;
    }
}

// ---------------- Kernel 2a: edge scalar path (low VGPR, no spill) ---------
// en = [ns[src],ns[dst]]@Wen+ben ; tm = en*(es@Wtp+btp) ;
// esu = sigmoid(silu(tm@Wg1+bg1)@Wg2+bg2)*co ; es_out = es+esu ; stash esu f32.
template<bool F32>
__global__ __launch_bounds__(256) void k_edge_s(
    const int* __restrict__ mode,
    const void* __restrict__ edge_s, const void* __restrict__ dist,
    const int* __restrict__ src, const int* __restrict__ dst,
    const void* __restrict__ Wen, const void* __restrict__ ben,
    const void* __restrict__ Wtp, const void* __restrict__ btp,
    const void* __restrict__ Wg1, const void* __restrict__ bg1,
    const void* __restrict__ Wg2, const void* __restrict__ bg2,
    const float* __restrict__ ns,
    float* __restrict__ esu_o, void* __restrict__ es_out)
{
    if ((mode[0] != 0) != F32) return;
    __shared__ float sWen[32*16];
    __shared__ float sWtp[256], sWg1[256], sWg2[256];
    __shared__ float sben[16], sbtp[16], sbg1[16], sbg2[16];
    const int tid = threadIdx.x;
    for (int i = tid; i < 512; i += 256) sWen[i] = ld1<F32>(Wen, i);
    sWtp[tid] = ld1<F32>(Wtp, tid);
    sWg1[tid] = ld1<F32>(Wg1, tid);
    sWg2[tid] = ld1<F32>(Wg2, tid);
    if (tid < 16){
        sben[tid] = ld1<F32>(ben, tid);
        sbtp[tid] = ld1<F32>(btp, tid);
        sbg1[tid] = ld1<F32>(bg1, tid);
        sbg2[tid] = ld1<F32>(bg2, tid);
    }
    __syncthreads();

    const int e = blockIdx.x * 256 + tid;    // EE = 3125*256
    const int s = src[e], d = dst[e];

    float en[16];
    {
        float nsS[16], nsD[16];
        const float4* ps = reinterpret_cast<const float4*>(ns + (size_t)s*16);
        const float4* pd = reinterpret_cast<const float4*>(ns + (size_t)d*16);
        #pragma unroll
        for (int k = 0; k < 4; k++){
            float4 a = ps[k]; nsS[4*k]=a.x; nsS[4*k+1]=a.y; nsS[4*k+2]=a.z; nsS[4*k+3]=a.w;
            float4 b = pd[k]; nsD[4*k]=b.x; nsD[4*k+1]=b.y; nsD[4*k+2]=b.z; nsD[4*k+3]=b.w;
        }
        #pragma unroll
        for (int j = 0; j < 16; j++){
            float a = sben[j];
            #pragma unroll
            for (int i = 0; i < 16; i++) a += nsS[i] * sWen[i*16 + j];
            #pragma unroll
            for (int i = 0; i < 16; i++) a += nsD[i] * sWen[(16+i)*16 + j];
            en[j] = a;
        }
    }
    float es[16];
    ld8v<F32>(edge_s, (size_t)e*16, es);
    ld8v<F32>(edge_s, (size_t)e*16 + 8, es + 8);
    float tm[16];
    #pragma unroll
    for (int j = 0; j < 16; j++){
        float a = sbtp[j];
        #pragma unroll
        for (int i = 0; i < 16; i++) a += es[i] * sWtp[i*16 + j];
        tm[j] = en[j] * a;
    }
    float g1[16];
    #pragma unroll
    for (int j = 0; j < 16; j++){
        float a = sbg1[j];
        #pragma unroll
        for (int i = 0; i < 16; i++) a += tm[i] * sWg1[i*16 + j];
        g1[j] = siluf(a);
    }
    const float dd = ld1<F32>(dist, e);
    const float co = (dd < 10.f) ? 0.5f * (cosf(dd * 0.3141592653589793f) + 1.f) : 0.f;
    float esu[16];
    #pragma unroll
    for (int j = 0; j < 16; j++){
        float a = sbg2[j];
        #pragma unroll
        for (int i = 0; i < 16; i++) a += g1[i] * sWg2[i*16 + j];
        esu[j] = sigmf(a) * co;
    }
    // stash esu (f32-exact)
    {
        float4* q = reinterpret_cast<float4*>(esu_o + (size_t)e*16);
        q[0] = make_float4(esu[0],esu[1],esu[2],esu[3]);
        q[1] = make_float4(esu[4],esu[5],esu[6],esu[7]);
        q[2] = make_float4(esu[8],esu[9],esu[10],esu[11]);
        q[3] = make_float4(esu[12],esu[13],esu[14],esu[15]);
    }
    float outv[16];
    #pragma unroll
    for (int j = 0; j < 16; j++) outv[j] = es[j] + esu[j];
    st8v<F32>(es_out, (size_t)e*16, outv);
    st8v<F32>(es_out, (size_t)e*16 + 8, outv + 8);
}

// ---------------- Kernel 2b: edge vector path (low VGPR, no spill) ---------
// vc = esu@Wtv+btv ; ev_out = edge_v + (edge_v*tc + nv[src]*ec + vctr*rc)*co
template<bool F32>
__global__ __launch_bounds__(256) void k_edge_v(
    const int* __restrict__ mode,
    const void* __restrict__ edge_v, const void* __restrict__ dist,
    const void* __restrict__ vctr, const int* __restrict__ src,
    const void* __restrict__ Wtv, const void* __restrict__ btv,
    const float* __restrict__ nv, const float* __restrict__ esu_i,
    void* __restrict__ ev_out)
{
    if ((mode[0] != 0) != F32) return;
    __shared__ float sWtv[16*48];
    __shared__ float sbtv[48];
    const int tid = threadIdx.x;
    for (int i = tid; i < 768; i += 256) sWtv[i] = ld1<F32>(Wtv, i);
    if (tid < 48) sbtv[tid] = ld1<F32>(btv, tid);
    __syncthreads();

    const int e = blockIdx.x * 256 + tid;    // EE = 3125*256
    const int s = src[e];

    float vc[48];
    {
        float esu[16];
        const float4* ep = reinterpret_cast<const float4*>(esu_i + (size_t)e*16);
        float4 q0 = ep[0], q1 = ep[1], q2 = ep[2], q3 = ep[3];
        esu[0]=q0.x;  esu[1]=q0.y;  esu[2]=q0.z;  esu[3]=q0.w;
        esu[4]=q1.x;  esu[5]=q1.y;  esu[6]=q1.z;  esu[7]=q1.w;
        esu[8]=q2.x;  esu[9]=q2.y;  esu[10]=q2.z; esu[11]=q2.w;
        esu[12]=q3.x; esu[13]=q3.y; esu[14]=q3.z; esu[15]=q3.w;
        #pragma unroll
        for (int j = 0; j < 48; j++){
            float a = sbtv[j];
            #pragma unroll
            for (int i = 0; i < 16; i++) a += esu[i] * sWtv[i*48 + j];
            vc[j] = a;
        }
    }
    const float dd = ld1<F32>(dist, e);
    const float co = (dd < 10.f) ? 0.5f * (cosf(dd * 0.3141592653589793f) + 1.f) : 0.f;
    float vnm[3];
    vnm[0] = ld1<F32>(vctr, (size_t)e*3 + 0);
    vnm[1] = ld1<F32>(vctr, (size_t)e*3 + 1);
    vnm[2] = ld1<F32>(vctr, (size_t)e*3 + 2);
    #pragma unroll
    for (int v = 0; v < 3; v++){
        float evv[16];
        ld8v<F32>(edge_v, (size_t)e*48 + v*16, evv);
        ld8v<F32>(edge_v, (size_t)e*48 + v*16 + 8, evv + 8);
        float nvv[16];
        {
            const float4* pv = reinterpret_cast<const float4*>(nv + (size_t)s*48 + v*16);
            #pragma unroll
            for (int k = 0; k < 4; k++){
                float4 a = pv[k]; nvv[4*k]=a.x; nvv[4*k+1]=a.y; nvv[4*k+2]=a.z; nvv[4*k+3]=a.w;
            }
        }
        float outv[16];
        #pragma unroll
        for (int j = 0; j < 16; j++){
            float u = (evv[j]*vc[j] + nvv[j]*vc[16+j] + vnm[v]*vc[32+j]) * co;
            outv[j] = evv[j] + u;
        }
        st8v<F32>(ev_out, (size_t)e*48 + v*16, outv);
        st8v<F32>(ev_out, (size_t)e*48 + v*16 + 8, outv + 8);
    }
}

// ---------------- Kernel 3: CSR gather + node output + norms ---------------
template<bool F32>
__global__ __launch_bounds__(256) void k_node_post(
    const int* __restrict__ mode,
    const void* __restrict__ node_s, const void* __restrict__ node_v,
    const float* __restrict__ esu_ws, const float* __restrict__ nvn, const float* __restrict__ nv,
    const void* __restrict__ edge_v, const void* __restrict__ dist, const void* __restrict__ vctr,
    const int* __restrict__ src,
    const int* __restrict__ off, const int* __restrict__ eidx,
    const void* __restrict__ Wtv, const void* __restrict__ btv,
    const void* __restrict__ Wonv, const void* __restrict__ Wo1, const void* __restrict__ bo1,
    const void* __restrict__ Wo2, const void* __restrict__ bo2,
    const void* __restrict__ ln_g, const void* __restrict__ ln_b, const void* __restrict__ cn,
    void* __restrict__ s_out, void* __restrict__ v_out)
{
    if ((mode[0] != 0) != F32) return;
    __shared__ float sWonv[16*128], sWo2[16*128], sWo1[32*16];
    __shared__ float sbo1[16], sbo2[128], slg[128], slb[128], scn[128];
    __shared__ float smess[4][32], sev[4][48], sh[4][16];
    const int tid = threadIdx.x;
    for (int i = tid; i < 2048; i += 256){
        sWonv[i] = ld1<F32>(Wonv, i);
        sWo2[i]  = ld1<F32>(Wo2, i);
    }
    for (int i = tid; i < 512; i += 256) sWo1[i] = ld1<F32>(Wo1, i);
    if (tid < 16) sbo1[tid] = ld1<F32>(bo1, tid);
    if (tid < 128){
        sbo2[tid] = ld1<F32>(bo2, tid);
        slg[tid]  = ld1<F32>(ln_g, tid);
        slb[tid]  = ld1<F32>(ln_b, tid);
        scn[tid]  = ld1<F32>(cn, tid);
    }

    const int w = tid >> 6, lane = tid & 63;
    const int n = blockIdx.x * 4 + w;        // NN = 12500*4
    const int j = lane & 15;
    const int vv = (lane >> 4) - 1;          // 0..2 for lanes >= 16
    const int c48 = lane - 16;               // v*16+j for lanes >= 16

    // hoist the three Wtv columns this lane needs into registers
    float wT[16], wE[16], wR[16];
    #pragma unroll
    for (int i = 0; i < 16; i++){
        wT[i] = ld1<F32>(Wtv, i*48 + j);
        wE[i] = ld1<F32>(Wtv, i*48 + 16 + j);
        wR[i] = ld1<F32>(Wtv, i*48 + 32 + j);
    }
    const float bT = ld1<F32>(btv, j);
    const float bE = ld1<F32>(btv, 16 + j);
    const float bR = ld1<F32>(btv, 32 + j);

    const int beg = off[n], end = off[n+1];
    float acc = 0.f;
    for (int t = beg; t < end; t++){
        const int e = eidx[t];
        float eu[16];
        {
            const float4* ep = reinterpret_cast<const float4*>(esu_ws + (size_t)e*16);
            float4 q0 = ep[0], q1 = ep[1], q2 = ep[2], q3 = ep[3];
            eu[0]=q0.x;  eu[1]=q0.y;  eu[2]=q0.z;  eu[3]=q0.w;
            eu[4]=q1.x;  eu[5]=q1.y;  eu[6]=q1.z;  eu[7]=q1.w;
            eu[8]=q2.x;  eu[9]=q2.y;  eu[10]=q2.z; eu[11]=q2.w;
            eu[12]=q3.x; eu[13]=q3.y; eu[14]=q3.z; eu[15]=q3.w;
        }
        if (lane < 16){
            acc += eu[j];
        } else {
            float tc = bT, ec = bE, rc = bR;
            #pragma unroll
            for (int i = 0; i < 16; i++){
                tc += eu[i] * wT[i];
                ec += eu[i] * wE[i];
                rc += eu[i] * wR[i];
            }
            const float dd = ld1<F32>(dist, e);
            const float co = (dd < 10.f) ? 0.5f * (cosf(dd * 0.3141592653589793f) + 1.f) : 0.f;
            const int se = src[e];
            const float ev  = ld1<F32>(edge_v, (size_t)e*48 + c48);
            const float nvq = nv[(size_t)se*48 + c48];
            const float vn  = ld1<F32>(vctr, (size_t)e*3 + vv);
            acc += (ev*tc + nvq*ec + vn*rc) * co;
        }
    }
    if (lane < 16){
        smess[w][lane]      = acc;                          // n_es
        smess[w][16 + lane] = nvn[(size_t)n*16 + lane];     // nv_norm
    } else {
        sev[w][c48] = acc;                                  // n_ev
    }
    __syncthreads();

    if (lane < 16){
        float a = sbo1[lane];
        #pragma unroll
        for (int i = 0; i < 32; i++) a += smess[w][i] * sWo1[i*16 + lane];
        sh[w][lane] = siluf(a);
    }
    __syncthreads();

    const int g0 = lane * 2;
    float s0, s1;
    {
        float r0, r1;
        ld2v<F32>(node_s, (size_t)n*128 + g0, r0, r1);
        float a0 = sbo2[g0], a1 = sbo2[g0+1];
        #pragma unroll
        for (int i = 0; i < 16; i++){
            float h = sh[w][i];
            a0 += h * sWo2[i*128 + g0];
            a1 += h * sWo2[i*128 + g0 + 1];
        }
        s0 = r0 + a0;
        s1 = r1 + a1;
    }
    float ssum = s0 + s1, ssq = s0*s0 + s1*s1;
    #pragma unroll
    for (int offd = 32; offd >= 1; offd >>= 1){
        ssum += __shfl_xor(ssum, offd, 64);
        ssq  += __shfl_xor(ssq,  offd, 64);
    }
    const float mean = ssum * (1.f/128.f);
    const float var  = ssq * (1.f/128.f) - mean*mean;
    const float rstd = rsqrtf(var + 1e-5f);
    {
        float o0 = (s0 - mean) * rstd * slg[g0]   + slb[g0];
        float o1 = (s1 - mean) * rstd * slg[g0+1] + slb[g0+1];
        st2v<F32>(s_out, (size_t)n*128 + g0, o0, o1);
    }
    float va[3], vb[3];
    #pragma unroll
    for (int v = 0; v < 3; v++){
        float r0, r1;
        ld2v<F32>(node_v, (size_t)n*384 + v*128 + g0, r0, r1);
        float a0 = 0.f, a1 = 0.f;
        #pragma unroll
        for (int i = 0; i < 16; i++){
            float x = sev[w][v*16 + i];
            a0 += x * sWonv[i*128 + g0];
            a1 += x * sWonv[i*128 + g0 + 1];
        }
        va[v] = r0 + a0;
        vb[v] = r1 + a1;
    }
    float n0 = fmaxf(sqrtf(va[0]*va[0] + va[1]*va[1] + va[2]*va[2]), 1e-8f);
    float n1 = fmaxf(sqrtf(vb[0]*vb[0] + vb[1]*vb[1] + vb[2]*vb[2]), 1e-8f);
    const float sc0 = scn[g0]   / n0;
    const float sc1 = scn[g0+1] / n1;
    #pragma unroll
    for (int v = 0; v < 3; v++){
        st2v<F32>(v_out, (size_t)n*384 + v*128 + g0, va[v]*sc0, vb[v]*sc1);
    }
}

extern "C" void kernel_launch(void* const* d_in, const int* in_sizes, int n_in,
                              void* d_out, int out_size, void* d_ws, size_t ws_size,
                              hipStream_t stream)
{
    (void)in_sizes; (void)n_in; (void)out_size; (void)ws_size;
    const void* node_s = d_in[0];
    const void* node_v = d_in[1];
    const void* edge_s = d_in[2];
    const void* edge_v = d_in[3];
    const void* dist   = d_in[4];
    const void* vctr   = d_in[5];
    const int*  src    = (const int*)d_in[6];
    const int*  dst    = (const int*)d_in[7];
    const void* Wns = d_in[8];  const void* bns = d_in[9];
    const void* Wnv = d_in[10];
    const void* Wen = d_in[11]; const void* ben = d_in[12];
    const void* Wtp = d_in[13]; const void* btp = d_in[14];
    const void* Wg1 = d_in[15]; const void* bg1 = d_in[16];
    const void* Wg2 = d_in[17]; const void* bg2 = d_in[18];
    const void* Wtv = d_in[19]; const void* btv = d_in[20];
    const void* Wonv= d_in[21];
    const void* Wo1 = d_in[22]; const void* bo1 = d_in[23];
    const void* Wo2 = d_in[24]; const void* bo2 = d_in[25];
    const void* lng = d_in[26]; const void* lnb = d_in[27];
    const void* cn  = d_in[28];

    float* ws   = (float*)d_ws;
    float* ns_  = ws;                          // NN*16
    float* nv_  = ns_  + (size_t)NN*16;        // NN*48
    float* nvn_ = nv_  + (size_t)NN*48;        // NN*16
    float* esu_ = nvn_ + (size_t)NN*16;        // EE*16  (51.2 MB)
    int*   off_ = (int*)(esu_ + (size_t)EE*16);// NN+1
    int*   cur_ = off_ + (NN + 1);             // NN  (counts, then cursor)
    int*   eidx_= cur_ + NN;                   // EE
    int*   flag = eidx_ + EE;

    // output layout: same element offsets for either dtype
    char* ob = (char*)d_out;
    const size_t esz_f32 = 4, esz_b16 = 2;
    const size_t off_v  = (size_t)NN*GG;
    const size_t off_es = off_v + (size_t)NN*3*GG;
    const size_t off_ev = off_es + (size_t)EE*LGD;

    hipMemsetAsync(cur_, 0, (size_t)NN*sizeof(int), stream);
    k_detect<<<1, 1024, 0, stream>>>((const u32*)node_s, flag);

    // CSR by dst (dtype-independent)
    k_hist<<<EE/256, 256, 0, stream>>>(dst, cur_);
    k_scan<<<1, 256, 0, stream>>>(cur_, off_);
    k_fill<<<EE/256, 256, 0, stream>>>(dst, cur_, eidx_);

    // bf16-mode pointer bases
    void* s_out_b  = ob;
    void* v_out_b  = ob + off_v  * esz_b16;
    void* es_out_b = ob + off_es * esz_b16;
    void* ev_out_b = ob + off_ev * esz_b16;
    // f32-mode pointer bases
    void* s_out_f  = ob;
    void* v_out_f  = ob + off_v  * esz_f32;
    void* es_out_f = ob + off_es * esz_f32;
    void* ev_out_f = ob + off_ev * esz_f32;

    k_node_pre<false><<<NN/4, 256, 0, stream>>>(flag, node_s, node_v, Wns, bns, Wnv, ns_, nv_, nvn_);
    k_node_pre<true ><<<NN/4, 256, 0, stream>>>(flag, node_s, node_v, Wns, bns, Wnv, ns_, nv_, nvn_);

    k_edge_s<false><<<EE/256, 256, 0, stream>>>(flag, edge_s, dist, src, dst,
        Wen, ben, Wtp, btp, Wg1, bg1, Wg2, bg2, ns_, esu_, es_out_b);
    k_edge_s<true ><<<EE/256, 256, 0, stream>>>(flag, edge_s, dist, src, dst,
        Wen, ben, Wtp, btp, Wg1, bg1, Wg2, bg2, ns_, esu_, es_out_f);

    k_edge_v<false><<<EE/256, 256, 0, stream>>>(flag, edge_v, dist, vctr, src,
        Wtv, btv, nv_, esu_, ev_out_b);
    k_edge_v<true ><<<EE/256, 256, 0, stream>>>(flag, edge_v, dist, vctr, src,
        Wtv, btv, nv_, esu_, ev_out_f);

    k_node_post<false><<<NN/4, 256, 0, stream>>>(flag, node_s, node_v, esu_, nvn_, nv_,
        edge_v, dist, vctr, src, off_, eidx_, Wtv, btv,
        Wonv, Wo1, bo1, Wo2, bo2, lng, lnb, cn, s_out_b, v_out_b);
    k_node_post<true ><<<NN/4, 256, 0, stream>>>(flag, node_s, node_v, esu_, nvn_, nv_,
        edge_v, dist, vctr, src, off_, eidx_, Wtv, btv,
        Wonv, Wo1, bo1, Wo2, bo2, lng, lnb, cn, s_out_f, v_out_f);
}

// Round 3
// 1586.160 us; speedup vs baseline: 2.4293x; 2.4293x over previous
//
#include <hip/hip_runtime.h>
#include <hip/hip_bf16.h>
#include <math.h>

#define NN 50000
#define EE 800000
#define GG 128
#define LGD 16

typedef unsigned int u32;
typedef __hip_bfloat16 bf16;

__device__ __forceinline__ float bflo(u32 u){ union{u32 x; float f;} c; c.x = u << 16; return c.f; }
__device__ __forceinline__ float bfhi(u32 u){ union{u32 x; float f;} c; c.x = u & 0xffff0000u; return c.f; }
__device__ __forceinline__ u32 f2bf(float f){
    union{float f; u32 u;} c; c.f = f;
    return (c.u + 0x7fffu + ((c.u >> 16) & 1u)) >> 16;  // RNE
}
__device__ __forceinline__ float siluf(float x){ return x / (1.f + expf(-x)); }
__device__ __forceinline__ float sigmf(float x){ return 1.f / (1.f + expf(-x)); }

// ---- dtype-polymorphic load/store: F32 ? float32 : bf16 -------------------
template<bool F32>
__device__ __forceinline__ float ld1(const void* p, size_t i){
    if (F32) return reinterpret_cast<const float*>(p)[i];
    return __bfloat162float(reinterpret_cast<const bf16*>(p)[i]);
}
template<bool F32>
__device__ __forceinline__ void st1(void* p, size_t i, float v){
    if (F32) reinterpret_cast<float*>(p)[i] = v;
    else reinterpret_cast<unsigned short*>(p)[i] = (unsigned short)f2bf(v);
}
template<bool F32>
__device__ __forceinline__ void ld8v(const void* p, size_t i, float* o){
    if (F32){
        const float4* q = reinterpret_cast<const float4*>(reinterpret_cast<const float*>(p) + i);
        float4 a = q[0], b = q[1];
        o[0]=a.x;o[1]=a.y;o[2]=a.z;o[3]=a.w;o[4]=b.x;o[5]=b.y;o[6]=b.z;o[7]=b.w;
    } else {
        uint4 q = *reinterpret_cast<const uint4*>(reinterpret_cast<const bf16*>(p) + i);
        o[0]=bflo(q.x);o[1]=bfhi(q.x);o[2]=bflo(q.y);o[3]=bfhi(q.y);
        o[4]=bflo(q.z);o[5]=bfhi(q.z);o[6]=bflo(q.w);o[7]=bfhi(q.w);
    }
}
template<bool F32>
__device__ __forceinline__ void ld2v(const void* p, size_t i, float& a, float& b){
    if (F32){ float2 q = *reinterpret_cast<const float2*>(reinterpret_cast<const float*>(p)+i); a=q.x; b=q.y; }
    else { u32 r = *reinterpret_cast<const u32*>(reinterpret_cast<const bf16*>(p)+i); a=bflo(r); b=bfhi(r); }
}
template<bool F32>
__device__ __forceinline__ void st2v(void* p, size_t i, float a, float b){
    if (F32){ *reinterpret_cast<float2*>(reinterpret_cast<float*>(p)+i) = make_float2(a,b); }
    else { *reinterpret_cast<u32*>(reinterpret_cast<bf16*>(p)+i) = f2bf(a) | (f2bf(b)<<16); }
}

// ---- dtype detector --------------------------------------------------------
__global__ __launch_bounds__(1024) void k_detect(const u32* __restrict__ q, int* __restrict__ flag){
    __shared__ int s;
    if (threadIdx.x == 0) s = 0;
    __syncthreads();
    int h = 0;
    #pragma unroll
    for (int i = 0; i < 4; i++){
        u32 w = q[threadIdx.x + i*1024];
        if ((w & 0x7F80u) == 0x7F80u) h = 1;
    }
    if (h) atomicOr(&s, 1);
    __syncthreads();
    if (threadIdx.x == 0) flag[0] = s;   // 1 = float32, 0 = bf16
}

// ---------------- CSR build (dtype-independent) ----------------------------
__global__ __launch_bounds__(256) void k_hist(const int* __restrict__ dst, int* __restrict__ cnt){
    const int e = blockIdx.x * 256 + threadIdx.x;
    atomicAdd(&cnt[dst[e]], 1);
}

__global__ __launch_bounds__(256) void k_scan(int* __restrict__ cur, int* __restrict__ off){
    const int S = 196;                // 256*196 = 50176 >= NN
    const int t = threadIdx.x;
    const int b0 = t * S;
    int lsum = 0;
    for (int k = 0; k < S; k++){
        int i = b0 + k;
        if (i < NN) lsum += cur[i];
    }
    __shared__ int ssum[256];
    ssum[t] = lsum;
    __syncthreads();
    #pragma unroll
    for (int d = 1; d < 256; d <<= 1){
        int tv = (t >= d) ? ssum[t - d] : 0;
        __syncthreads();
        ssum[t] += tv;
        __syncthreads();
    }
    int run = ssum[t] - lsum;         // exclusive strip offset
    for (int k = 0; k < S; k++){
        int i = b0 + k;
        if (i >= NN) break;
        int c = cur[i];
        off[i] = run;
        cur[i] = run;
        run += c;
    }
    if (t == 255) off[NN] = run;      // = EE
}

__global__ __launch_bounds__(256) void k_fill(const int* __restrict__ dst, int* __restrict__ cur,
                                              int* __restrict__ eidx){
    const int e = blockIdx.x * 256 + threadIdx.x;
    const int p = atomicAdd(&cur[dst[e]], 1);
    eidx[p] = e;
}

// ---------------- Kernel 1: node input projections + Wen hoist -------------
// preS = silu(node_s@Wns+bns)@Wen[0:16] ; preD = same@Wen[16:32]
template<bool F32>
__global__ __launch_bounds__(256) void k_node_pre(
    const int* __restrict__ mode,
    const void* __restrict__ node_s, const void* __restrict__ node_v,
    const void* __restrict__ Wns, const void* __restrict__ bns,
    const void* __restrict__ Wnv, const void* __restrict__ Wen,
    float* __restrict__ preS, float* __restrict__ preD,
    float* __restrict__ nv, float* __restrict__ nvn)
{
    if ((mode[0] != 0) != F32) return;
    __shared__ float sWns[GG*LGD];
    __shared__ float sWnv[GG*LGD];
    __shared__ float sWen[32*16];
    __shared__ float sb[LGD];
    __shared__ float sbuf[4][512];
    const int tid = threadIdx.x;
    for (int i = tid; i < GG*LGD; i += 256){
        sWns[i] = ld1<F32>(Wns, i);
        sWnv[i] = ld1<F32>(Wnv, i);
    }
    for (int i = tid; i < 512; i += 256) sWen[i] = ld1<F32>(Wen, i);
    if (tid < LGD) sb[tid] = ld1<F32>(bns, tid);
    __syncthreads();

    const int w = tid >> 6, lane = tid & 63, c = lane & 15;
    const int n = blockIdx.x * 4 + w;        // NN = 12500*4
    {
        float tmp[8];
        if (lane < 16){
            ld8v<F32>(node_s, (size_t)n*GG + lane*8, tmp);
            float4* dp = reinterpret_cast<float4*>(&sbuf[w][lane*8]);
            dp[0] = make_float4(tmp[0],tmp[1],tmp[2],tmp[3]);
            dp[1] = make_float4(tmp[4],tmp[5],tmp[6],tmp[7]);
        } else {
            ld8v<F32>(node_v, (size_t)n*384 + (lane-16)*8, tmp);
            float4* dp = reinterpret_cast<float4*>(&sbuf[w][128 + (lane-16)*8]);
            dp[0] = make_float4(tmp[0],tmp[1],tmp[2],tmp[3]);
            dp[1] = make_float4(tmp[4],tmp[5],tmp[6],tmp[7]);
        }
    }
    __syncthreads();

    float acc;
    if (lane < 16){
        acc = sb[c];
        #pragma unroll 16
        for (int k = 0; k < GG; k++) acc += sbuf[w][k] * sWns[k*LGD + c];
    } else {
        const int v = (lane >> 4) - 1;
        const float* vb = &sbuf[w][128 + v*128];
        acc = 0.f;
        #pragma unroll 16
        for (int k = 0; k < GG; k++) acc += vb[k] * sWnv[k*LGD + c];
    }
    float v1 = __shfl(acc, 16 + c, 64);
    float v2 = __shfl(acc, 32 + c, 64);
    float v3 = __shfl(acc, 48 + c, 64);
    if (lane < 16){
        const float sns = siluf(acc);
        nvn[(size_t)n*16 + c] = sqrtf(v1*v1 + v2*v2 + v3*v3 + 1e-12f);
        float pS = 0.f, pD = 0.f;
        #pragma unroll
        for (int i = 0; i < 16; i++){
            float x = __shfl(sns, i, 16);   // lanes 0-15: own 16-group
            pS += x * sWen[i*16 + c];
            pD += x * sWen[(16+i)*16 + c];
        }
        preS[(size_t)n*16 + c] = pS;
        preD[(size_t)n*16 + c] = pD;
    } else {
        nv[(size_t)n*48 + (lane - 16)] = acc;
    }
}

// ---------------- Kernel 2: fused edge update, feature-parallel ------------
// 16 lanes per edge; lane j owns feature j. Weights column-cached in VGPRs;
// cross-feature reductions via __shfl within 16-lane groups. Zero LDS.
template<bool F32>
__global__ __launch_bounds__(256, 3) void k_edge(
    const int* __restrict__ mode,
    const void* __restrict__ edge_s, const void* __restrict__ edge_v,
    const void* __restrict__ dist, const void* __restrict__ vctr,
    const int* __restrict__ src, const int* __restrict__ dst,
    const void* __restrict__ ben,
    const void* __restrict__ Wtp, const void* __restrict__ btp,
    const void* __restrict__ Wg1, const void* __restrict__ bg1,
    const void* __restrict__ Wg2, const void* __restrict__ bg2,
    const void* __restrict__ Wtv, const void* __restrict__ btv,
    const float* __restrict__ preS, const float* __restrict__ preD,
    const float* __restrict__ nv,
    float* __restrict__ esu_o,
    void* __restrict__ es_out, void* __restrict__ ev_out)
{
    if ((mode[0] != 0) != F32) return;
    const int t = blockIdx.x * 256 + threadIdx.x;   // EE*16 threads
    const int e = t >> 4;
    const int j = t & 15;

    // per-lane weight columns (one-time, L1-resident: weights total < 6 KB)
    float wtp[16], wg1[16], wg2[16], wT[16], wE[16], wR[16];
    #pragma unroll
    for (int i = 0; i < 16; i++){
        wtp[i] = ld1<F32>(Wtp, i*16 + j);
        wg1[i] = ld1<F32>(Wg1, i*16 + j);
        wg2[i] = ld1<F32>(Wg2, i*16 + j);
        wT[i]  = ld1<F32>(Wtv, i*48 + j);
        wE[i]  = ld1<F32>(Wtv, i*48 + 16 + j);
        wR[i]  = ld1<F32>(Wtv, i*48 + 32 + j);
    }
    const float bben = ld1<F32>(ben, j);
    const float bbtp = ld1<F32>(btp, j);
    const float bbg1 = ld1<F32>(bg1, j);
    const float bbg2 = ld1<F32>(bg2, j);
    const float bT = ld1<F32>(btv, j);
    const float bE = ld1<F32>(btv, 16 + j);
    const float bR = ld1<F32>(btv, 32 + j);

    const int s = src[e], d = dst[e];
    const float dd = ld1<F32>(dist, e);
    const float co = (dd < 10.f) ? 0.5f * (cosf(dd * 0.3141592653589793f) + 1.f) : 0.f;

    // en_j = preS[s][j] + preD[d][j] + ben_j   (Wen matmul hoisted to nodes)
    const float enj = preS[(size_t)s*16 + j] + preD[(size_t)d*16 + j] + bben;
    const float esj = ld1<F32>(edge_s, (size_t)e*16 + j);

    // tm_j = en_j * (es@Wtp + btp)_j
    float tp = bbtp;
    #pragma unroll
    for (int i = 0; i < 16; i++) tp += __shfl(esj, i, 16) * wtp[i];
    const float tmj = enj * tp;

    float a = bbg1;
    #pragma unroll
    for (int i = 0; i < 16; i++) a += __shfl(tmj, i, 16) * wg1[i];
    const float g1j = siluf(a);

    a = bbg2;
    #pragma unroll
    for (int i = 0; i < 16; i++) a += __shfl(g1j, i, 16) * wg2[i];
    const float esuj = sigmf(a) * co;

    esu_o[(size_t)e*16 + j] = esuj;                 // f32-exact stash
    st1<F32>(es_out, (size_t)e*16 + j, esj + esuj); // edge_s residual

    // vc columns (T/E/R) for this feature
    float vT = bT, vE = bE, vR = bR;
    #pragma unroll
    for (int i = 0; i < 16; i++){
        float x = __shfl(esuj, i, 16);
        vT += x * wT[i];
        vE += x * wE[i];
        vR += x * wR[i];
    }

    #pragma unroll
    for (int v = 0; v < 3; v++){
        const float evj = ld1<F32>(edge_v, (size_t)e*48 + v*16 + j);
        const float nvj = nv[(size_t)s*48 + v*16 + j];
        const float vn  = ld1<F32>(vctr, (size_t)e*3 + v);
        const float u = (evj*vT + nvj*vE + vn*vR) * co;
        st1<F32>(ev_out, (size_t)e*48 + v*16 + j, evj + u);
    }
}

// ---------------- Kernel 3: CSR gather + node output + norms ---------------
template<bool F32>
__global__ __launch_bounds__(256) void k_node_post(
    const int* __restrict__ mode,
    const void* __restrict__ node_s, const void* __restrict__ node_v,
    const float* __restrict__ esu_ws, const float* __restrict__ nvn, const float* __restrict__ nv,
    const void* __restrict__ edge_v, const void* __restrict__ dist, const void* __restrict__ vctr,
    const int* __restrict__ src,
    const int* __restrict__ off, const int* __restrict__ eidx,
    const void* __restrict__ Wtv, const void* __restrict__ btv,
    const void* __restrict__ Wonv, const void* __restrict__ Wo1, const void* __restrict__ bo1,
    const void* __restrict__ Wo2, const void* __restrict__ bo2,
    const void* __restrict__ ln_g, const void* __restrict__ ln_b, const void* __restrict__ cn,
    void* __restrict__ s_out, void* __restrict__ v_out)
{
    if ((mode[0] != 0) != F32) return;
    __shared__ float sWonv[16*128], sWo2[16*128], sWo1[32*16];
    __shared__ float sbo1[16], sbo2[128], slg[128], slb[128], scn[128];
    __shared__ float smess[4][32], sev[4][48], sh[4][16];
    const int tid = threadIdx.x;
    for (int i = tid; i < 2048; i += 256){
        sWonv[i] = ld1<F32>(Wonv, i);
        sWo2[i]  = ld1<F32>(Wo2, i);
    }
    for (int i = tid; i < 512; i += 256) sWo1[i] = ld1<F32>(Wo1, i);
    if (tid < 16) sbo1[tid] = ld1<F32>(bo1, tid);
    if (tid < 128){
        sbo2[tid] = ld1<F32>(bo2, tid);
        slg[tid]  = ld1<F32>(ln_g, tid);
        slb[tid]  = ld1<F32>(ln_b, tid);
        scn[tid]  = ld1<F32>(cn, tid);
    }

    const int w = tid >> 6, lane = tid & 63;
    const int n = blockIdx.x * 4 + w;        // NN = 12500*4
    const int j = lane & 15;
    const int vv = (lane >> 4) - 1;          // 0..2 for lanes >= 16
    const int c48 = lane - 16;               // v*16+j for lanes >= 16

    // hoist the three Wtv columns this lane needs into registers
    float wT[16], wE[16], wR[16];
    #pragma unroll
    for (int i = 0; i < 16; i++){
        wT[i] = ld1<F32>(Wtv, i*48 + j);
        wE[i] = ld1<F32>(Wtv, i*48 + 16 + j);
        wR[i] = ld1<F32>(Wtv, i*48 + 32 + j);
    }
    const float bT = ld1<F32>(btv, j);
    const float bE = ld1<F32>(btv, 16 + j);
    const float bR = ld1<F32>(btv, 32 + j);

    const int beg = off[n], end = off[n+1];
    float acc = 0.f;
    for (int t = beg; t < end; t++){
        const int e = eidx[t];
        float eu[16];
        {
            const float4* ep = reinterpret_cast<const float4*>(esu_ws + (size_t)e*16);
            float4 q0 = ep[0], q1 = ep[1], q2 = ep[2], q3 = ep[3];
            eu[0]=q0.x;  eu[1]=q0.y;  eu[2]=q0.z;  eu[3]=q0.w;
            eu[4]=q1.x;  eu[5]=q1.y;  eu[6]=q1.z;  eu[7]=q1.w;
            eu[8]=q2.x;  eu[9]=q2.y;  eu[10]=q2.z; eu[11]=q2.w;
            eu[12]=q3.x; eu[13]=q3.y; eu[14]=q3.z; eu[15]=q3.w;
        }
        if (lane < 16){
            acc += eu[j];
        } else {
            float tc = bT, ec = bE, rc = bR;
            #pragma unroll
            for (int i = 0; i < 16; i++){
                tc += eu[i] * wT[i];
                ec += eu[i] * wE[i];
                rc += eu[i] * wR[i];
            }
            const float dd = ld1<F32>(dist, e);
            const float co = (dd < 10.f) ? 0.5f * (cosf(dd * 0.3141592653589793f) + 1.f) : 0.f;
            const int se = src[e];
            const float ev  = ld1<F32>(edge_v, (size_t)e*48 + c48);
            const float nvq = nv[(size_t)se*48 + c48];
            const float vn  = ld1<F32>(vctr, (size_t)e*3 + vv);
            acc += (ev*tc + nvq*ec + vn*rc) * co;
        }
    }
    if (lane < 16){
        smess[w][lane]      = acc;                          // n_es
        smess[w][16 + lane] = nvn[(size_t)n*16 + lane];     // nv_norm
    } else {
        sev[w][c48] = acc;                                  // n_ev
    }
    __syncthreads();

    if (lane < 16){
        float a = sbo1[lane];
        #pragma unroll
        for (int i = 0; i < 32; i++) a += smess[w][i] * sWo1[i*16 + lane];
        sh[w][lane] = siluf(a);
    }
    __syncthreads();

    const int g0 = lane * 2;
    float s0, s1;
    {
        float r0, r1;
        ld2v<F32>(node_s, (size_t)n*128 + g0, r0, r1);
        float a0 = sbo2[g0], a1 = sbo2[g0+1];
        #pragma unroll
        for (int i = 0; i < 16; i++){
            float h = sh[w][i];
            a0 += h * sWo2[i*128 + g0];
            a1 += h * sWo2[i*128 + g0 + 1];
        }
        s0 = r0 + a0;
        s1 = r1 + a1;
    }
    float ssum = s0 + s1, ssq = s0*s0 + s1*s1;
    #pragma unroll
    for (int offd = 32; offd >= 1; offd >>= 1){
        ssum += __shfl_xor(ssum, offd, 64);
        ssq  += __shfl_xor(ssq,  offd, 64);
    }
    const float mean = ssum * (1.f/128.f);
    const float var  = ssq * (1.f/128.f) - mean*mean;
    const float rstd = rsqrtf(var + 1e-5f);
    {
        float o0 = (s0 - mean) * rstd * slg[g0]   + slb[g0];
        float o1 = (s1 - mean) * rstd * slg[g0+1] + slb[g0+1];
        st2v<F32>(s_out, (size_t)n*128 + g0, o0, o1);
    }
    float va[3], vb[3];
    #pragma unroll
    for (int v = 0; v < 3; v++){
        float r0, r1;
        ld2v<F32>(node_v, (size_t)n*384 + v*128 + g0, r0, r1);
        float a0 = 0.f, a1 = 0.f;
        #pragma unroll
        for (int i = 0; i < 16; i++){
            float x = sev[w][v*16 + i];
            a0 += x * sWonv[i*128 + g0];
            a1 += x * sWonv[i*128 + g0 + 1];
        }
        va[v] = r0 + a0;
        vb[v] = r1 + a1;
    }
    float n0 = fmaxf(sqrtf(va[0]*va[0] + va[1]*va[1] + va[2]*va[2]), 1e-8f);
    float n1 = fmaxf(sqrtf(vb[0]*vb[0] + vb[1]*vb[1] + vb[2]*vb[2]), 1e-8f);
    const float sc0 = scn[g0]   / n0;
    const float sc1 = scn[g0+1] / n1;
    #pragma unroll
    for (int v = 0; v < 3; v++){
        st2v<F32>(v_out, (size_t)n*384 + v*128 + g0, va[v]*sc0, vb[v]*sc1);
    }
}

extern "C" void kernel_launch(void* const* d_in, const int* in_sizes, int n_in,
                              void* d_out, int out_size, void* d_ws, size_t ws_size,
                              hipStream_t stream)
{
    (void)in_sizes; (void)n_in; (void)out_size; (void)ws_size;
    const void* node_s = d_in[0];
    const void* node_v = d_in[1];
    const void* edge_s = d_in[2];
    const void* edge_v = d_in[3];
    const void* dist   = d_in[4];
    const void* vctr   = d_in[5];
    const int*  src    = (const int*)d_in[6];
    const int*  dst    = (const int*)d_in[7];
    const void* Wns = d_in[8];  const void* bns = d_in[9];
    const void* Wnv = d_in[10];
    const void* Wen = d_in[11]; const void* ben = d_in[12];
    const void* Wtp = d_in[13]; const void* btp = d_in[14];
    const void* Wg1 = d_in[15]; const void* bg1 = d_in[16];
    const void* Wg2 = d_in[17]; const void* bg2 = d_in[18];
    const void* Wtv = d_in[19]; const void* btv = d_in[20];
    const void* Wonv= d_in[21];
    const void* Wo1 = d_in[22]; const void* bo1 = d_in[23];
    const void* Wo2 = d_in[24]; const void* bo2 = d_in[25];
    const void* lng = d_in[26]; const void* lnb = d_in[27];
    const void* cn  = d_in[28];

    float* ws    = (float*)d_ws;
    float* preS_ = ws;                          // NN*16
    float* preD_ = preS_ + (size_t)NN*16;       // NN*16
    float* nv_   = preD_ + (size_t)NN*16;       // NN*48
    float* nvn_  = nv_   + (size_t)NN*48;       // NN*16
    float* esu_  = nvn_  + (size_t)NN*16;       // EE*16  (51.2 MB)
    int*   off_  = (int*)(esu_ + (size_t)EE*16);// NN+1
    int*   cur_  = off_ + (NN + 1);             // NN  (counts, then cursor)
    int*   eidx_ = cur_ + NN;                   // EE
    int*   flag  = eidx_ + EE;

    // output layout: same element offsets for either dtype
    char* ob = (char*)d_out;
    const size_t esz_f32 = 4, esz_b16 = 2;
    const size_t off_v  = (size_t)NN*GG;
    const size_t off_es = off_v + (size_t)NN*3*GG;
    const size_t off_ev = off_es + (size_t)EE*LGD;

    hipMemsetAsync(cur_, 0, (size_t)NN*sizeof(int), stream);
    k_detect<<<1, 1024, 0, stream>>>((const u32*)node_s, flag);

    // CSR by dst (dtype-independent)
    k_hist<<<EE/256, 256, 0, stream>>>(dst, cur_);
    k_scan<<<1, 256, 0, stream>>>(cur_, off_);
    k_fill<<<EE/256, 256, 0, stream>>>(dst, cur_, eidx_);

    // bf16-mode pointer bases
    void* s_out_b  = ob;
    void* v_out_b  = ob + off_v  * esz_b16;
    void* es_out_b = ob + off_es * esz_b16;
    void* ev_out_b = ob + off_ev * esz_b16;
    // f32-mode pointer bases
    void* s_out_f  = ob;
    void* v_out_f  = ob + off_v  * esz_f32;
    void* es_out_f = ob + off_es * esz_f32;
    void* ev_out_f = ob + off_ev * esz_f32;

    k_node_pre<false><<<NN/4, 256, 0, stream>>>(flag, node_s, node_v, Wns, bns, Wnv, Wen,
        preS_, preD_, nv_, nvn_);
    k_node_pre<true ><<<NN/4, 256, 0, stream>>>(flag, node_s, node_v, Wns, bns, Wnv, Wen,
        preS_, preD_, nv_, nvn_);

    // feature-parallel fused edge kernel: EE*16 threads
    k_edge<false><<<EE/16, 256, 0, stream>>>(flag, edge_s, edge_v, dist, vctr, src, dst,
        ben, Wtp, btp, Wg1, bg1, Wg2, bg2, Wtv, btv,
        preS_, preD_, nv_, esu_, es_out_b, ev_out_b);
    k_edge<true ><<<EE/16, 256, 0, stream>>>(flag, edge_s, edge_v, dist, vctr, src, dst,
        ben, Wtp, btp, Wg1, bg1, Wg2, bg2, Wtv, btv,
        preS_, preD_, nv_, esu_, es_out_f, ev_out_f);

    k_node_post<false><<<NN/4, 256, 0, stream>>>(flag, node_s, node_v, esu_, nvn_, nv_,
        edge_v, dist, vctr, src, off_, eidx_, Wtv, btv,
        Wonv, Wo1, bo1, Wo2, bo2, lng, lnb, cn, s_out_b, v_out_b);
    k_node_post<true ><<<NN/4, 256, 0, stream>>>(flag, node_s, node_v, esu_, nvn_, nv_,
        edge_v, dist, vctr, src, off_, eidx_, Wtv, btv,
        Wonv, Wo1, bo1, Wo2, bo2, lng, lnb, cn, s_out_f, v_out_f);
}

// Round 4
// 1263.162 us; speedup vs baseline: 3.0504x; 1.2557x over previous
//
#include <hip/hip_runtime.h>
#include <hip/hip_bf16.h>
#include <math.h>

#define NN 50000
#define EE 800000
#define GG 128
#define LGD 16

typedef unsigned int u32;
typedef __hip_bfloat16 bf16;

__device__ __forceinline__ float bflo(u32 u){ union{u32 x; float f;} c; c.x = u << 16; return c.f; }
__device__ __forceinline__ float bfhi(u32 u){ union{u32 x; float f;} c; c.x = u & 0xffff0000u; return c.f; }
__device__ __forceinline__ u32 f2bf(float f){
    union{float f; u32 u;} c; c.f = f;
    return (c.u + 0x7fffu + ((c.u >> 16) & 1u)) >> 16;  // RNE
}
__device__ __forceinline__ float siluf(float x){ return x / (1.f + expf(-x)); }
__device__ __forceinline__ float sigmf(float x){ return 1.f / (1.f + expf(-x)); }

// ---- dtype-polymorphic load/store: F32 ? float32 : bf16 -------------------
template<bool F32>
__device__ __forceinline__ float ld1(const void* p, size_t i){
    if (F32) return reinterpret_cast<const float*>(p)[i];
    return __bfloat162float(reinterpret_cast<const bf16*>(p)[i]);
}
template<bool F32>
__device__ __forceinline__ void st1(void* p, size_t i, float v){
    if (F32) reinterpret_cast<float*>(p)[i] = v;
    else reinterpret_cast<unsigned short*>(p)[i] = (unsigned short)f2bf(v);
}
template<bool F32>
__device__ __forceinline__ void ld8v(const void* p, size_t i, float* o){
    if (F32){
        const float4* q = reinterpret_cast<const float4*>(reinterpret_cast<const float*>(p) + i);
        float4 a = q[0], b = q[1];
        o[0]=a.x;o[1]=a.y;o[2]=a.z;o[3]=a.w;o[4]=b.x;o[5]=b.y;o[6]=b.z;o[7]=b.w;
    } else {
        uint4 q = *reinterpret_cast<const uint4*>(reinterpret_cast<const bf16*>(p) + i);
        o[0]=bflo(q.x);o[1]=bfhi(q.x);o[2]=bflo(q.y);o[3]=bfhi(q.y);
        o[4]=bflo(q.z);o[5]=bfhi(q.z);o[6]=bflo(q.w);o[7]=bfhi(q.w);
    }
}
template<bool F32>
__device__ __forceinline__ void ld2v(const void* p, size_t i, float& a, float& b){
    if (F32){ float2 q = *reinterpret_cast<const float2*>(reinterpret_cast<const float*>(p)+i); a=q.x; b=q.y; }
    else { u32 r = *reinterpret_cast<const u32*>(reinterpret_cast<const bf16*>(p)+i); a=bflo(r); b=bfhi(r); }
}
template<bool F32>
__device__ __forceinline__ void st2v(void* p, size_t i, float a, float b){
    if (F32){ *reinterpret_cast<float2*>(reinterpret_cast<float*>(p)+i) = make_float2(a,b); }
    else { *reinterpret_cast<u32*>(reinterpret_cast<bf16*>(p)+i) = f2bf(a) | (f2bf(b)<<16); }
}

// ---- dtype detector --------------------------------------------------------
__global__ __launch_bounds__(1024) void k_detect(const u32* __restrict__ q, int* __restrict__ flag){
    __shared__ int s;
    if (threadIdx.x == 0) s = 0;
    __syncthreads();
    int h = 0;
    #pragma unroll
    for (int i = 0; i < 4; i++){
        u32 w = q[threadIdx.x + i*1024];
        if ((w & 0x7F80u) == 0x7F80u) h = 1;
    }
    if (h) atomicOr(&s, 1);
    __syncthreads();
    if (threadIdx.x == 0) flag[0] = s;   // 1 = float32, 0 = bf16
}

// ---------------- CSR build (dtype-independent) ----------------------------
__global__ __launch_bounds__(256) void k_hist(const int* __restrict__ dst, int* __restrict__ cnt){
    const int e = blockIdx.x * 256 + threadIdx.x;
    atomicAdd(&cnt[dst[e]], 1);
}

__global__ __launch_bounds__(256) void k_scan(int* __restrict__ cur, int* __restrict__ off){
    const int S = 196;                // 256*196 = 50176 >= NN
    const int t = threadIdx.x;
    const int b0 = t * S;
    int lsum = 0;
    for (int k = 0; k < S; k++){
        int i = b0 + k;
        if (i < NN) lsum += cur[i];
    }
    __shared__ int ssum[256];
    ssum[t] = lsum;
    __syncthreads();
    #pragma unroll
    for (int d = 1; d < 256; d <<= 1){
        int tv = (t >= d) ? ssum[t - d] : 0;
        __syncthreads();
        ssum[t] += tv;
        __syncthreads();
    }
    int run = ssum[t] - lsum;         // exclusive strip offset
    for (int k = 0; k < S; k++){
        int i = b0 + k;
        if (i >= NN) break;
        int c = cur[i];
        off[i] = run;
        cur[i] = run;
        run += c;
    }
    if (t == 255) off[NN] = run;      // = EE
}

__global__ __launch_bounds__(256) void k_fill(const int* __restrict__ dst, int* __restrict__ cur,
                                              int* __restrict__ eidx){
    const int e = blockIdx.x * 256 + threadIdx.x;
    const int p = atomicAdd(&cur[dst[e]], 1);
    eidx[p] = e;
}

// ---------------- Kernel 1: node input projections + Wen hoist -------------
template<bool F32>
__global__ __launch_bounds__(256) void k_node_pre(
    const int* __restrict__ mode,
    const void* __restrict__ node_s, const void* __restrict__ node_v,
    const void* __restrict__ Wns, const void* __restrict__ bns,
    const void* __restrict__ Wnv, const void* __restrict__ Wen,
    float* __restrict__ preS, float* __restrict__ preD,
    float* __restrict__ nv, float* __restrict__ nvn)
{
    if ((mode[0] != 0) != F32) return;
    __shared__ float sWns[GG*LGD];
    __shared__ float sWnv[GG*LGD];
    __shared__ float sWen[32*16];
    __shared__ float sb[LGD];
    __shared__ float sbuf[4][512];
    const int tid = threadIdx.x;
    for (int i = tid; i < GG*LGD; i += 256){
        sWns[i] = ld1<F32>(Wns, i);
        sWnv[i] = ld1<F32>(Wnv, i);
    }
    for (int i = tid; i < 512; i += 256) sWen[i] = ld1<F32>(Wen, i);
    if (tid < LGD) sb[tid] = ld1<F32>(bns, tid);
    __syncthreads();

    const int w = tid >> 6, lane = tid & 63, c = lane & 15;
    const int n = blockIdx.x * 4 + w;        // NN = 12500*4
    {
        float tmp[8];
        if (lane < 16){
            ld8v<F32>(node_s, (size_t)n*GG + lane*8, tmp);
            float4* dp = reinterpret_cast<float4*>(&sbuf[w][lane*8]);
            dp[0] = make_float4(tmp[0],tmp[1],tmp[2],tmp[3]);
            dp[1] = make_float4(tmp[4],tmp[5],tmp[6],tmp[7]);
        } else {
            ld8v<F32>(node_v, (size_t)n*384 + (lane-16)*8, tmp);
            float4* dp = reinterpret_cast<float4*>(&sbuf[w][128 + (lane-16)*8]);
            dp[0] = make_float4(tmp[0],tmp[1],tmp[2],tmp[3]);
            dp[1] = make_float4(tmp[4],tmp[5],tmp[6],tmp[7]);
        }
    }
    __syncthreads();

    float acc;
    if (lane < 16){
        acc = sb[c];
        #pragma unroll 16
        for (int k = 0; k < GG; k++) acc += sbuf[w][k] * sWns[k*LGD + c];
    } else {
        const int v = (lane >> 4) - 1;
        const float* vb = &sbuf[w][128 + v*128];
        acc = 0.f;
        #pragma unroll 16
        for (int k = 0; k < GG; k++) acc += vb[k] * sWnv[k*LGD + c];
    }
    float v1 = __shfl(acc, 16 + c, 64);
    float v2 = __shfl(acc, 32 + c, 64);
    float v3 = __shfl(acc, 48 + c, 64);
    if (lane < 16){
        const float sns = siluf(acc);
        nvn[(size_t)n*16 + c] = sqrtf(v1*v1 + v2*v2 + v3*v3 + 1e-12f);
        float pS = 0.f, pD = 0.f;
        #pragma unroll
        for (int i = 0; i < 16; i++){
            float x = __shfl(sns, i, 16);   // lanes 0-15: own 16-group
            pS += x * sWen[i*16 + c];
            pD += x * sWen[(16+i)*16 + c];
        }
        preS[(size_t)n*16 + c] = pS;
        preD[(size_t)n*16 + c] = pD;
    } else {
        nv[(size_t)n*48 + (lane - 16)] = acc;
    }
}

// ---------------- Kernel 2: fused edge update, feature-parallel ------------
// 16 lanes per edge; lane j owns feature j. Weights column-cached in VGPRs;
// cross-feature reductions via __shfl within 16-lane groups. Zero LDS.
// If evu_o != nullptr, also stash the per-edge vector update u (f32-exact)
// so k_node_post's gather needs no recompute.
template<bool F32>
__global__ __launch_bounds__(256, 3) void k_edge(
    const int* __restrict__ mode,
    const void* __restrict__ edge_s, const void* __restrict__ edge_v,
    const void* __restrict__ dist, const void* __restrict__ vctr,
    const int* __restrict__ src, const int* __restrict__ dst,
    const void* __restrict__ ben,
    const void* __restrict__ Wtp, const void* __restrict__ btp,
    const void* __restrict__ Wg1, const void* __restrict__ bg1,
    const void* __restrict__ Wg2, const void* __restrict__ bg2,
    const void* __restrict__ Wtv, const void* __restrict__ btv,
    const float* __restrict__ preS, const float* __restrict__ preD,
    const float* __restrict__ nv,
    float* __restrict__ esu_o, float* __restrict__ evu_o,
    void* __restrict__ es_out, void* __restrict__ ev_out)
{
    if ((mode[0] != 0) != F32) return;
    const int t = blockIdx.x * 256 + threadIdx.x;   // EE*16 threads
    const int e = t >> 4;
    const int j = t & 15;

    // per-lane weight columns (one-time, L1-resident: weights total < 6 KB)
    float wtp[16], wg1[16], wg2[16], wT[16], wE[16], wR[16];
    #pragma unroll
    for (int i = 0; i < 16; i++){
        wtp[i] = ld1<F32>(Wtp, i*16 + j);
        wg1[i] = ld1<F32>(Wg1, i*16 + j);
        wg2[i] = ld1<F32>(Wg2, i*16 + j);
        wT[i]  = ld1<F32>(Wtv, i*48 + j);
        wE[i]  = ld1<F32>(Wtv, i*48 + 16 + j);
        wR[i]  = ld1<F32>(Wtv, i*48 + 32 + j);
    }
    const float bben = ld1<F32>(ben, j);
    const float bbtp = ld1<F32>(btp, j);
    const float bbg1 = ld1<F32>(bg1, j);
    const float bbg2 = ld1<F32>(bg2, j);
    const float bT = ld1<F32>(btv, j);
    const float bE = ld1<F32>(btv, 16 + j);
    const float bR = ld1<F32>(btv, 32 + j);

    const int s = src[e], d = dst[e];
    const float dd = ld1<F32>(dist, e);
    const float co = (dd < 10.f) ? 0.5f * (cosf(dd * 0.3141592653589793f) + 1.f) : 0.f;

    // en_j = preS[s][j] + preD[d][j] + ben_j   (Wen matmul hoisted to nodes)
    const float enj = preS[(size_t)s*16 + j] + preD[(size_t)d*16 + j] + bben;
    const float esj = ld1<F32>(edge_s, (size_t)e*16 + j);

    // tm_j = en_j * (es@Wtp + btp)_j
    float tp = bbtp;
    #pragma unroll
    for (int i = 0; i < 16; i++) tp += __shfl(esj, i, 16) * wtp[i];
    const float tmj = enj * tp;

    float a = bbg1;
    #pragma unroll
    for (int i = 0; i < 16; i++) a += __shfl(tmj, i, 16) * wg1[i];
    const float g1j = siluf(a);

    a = bbg2;
    #pragma unroll
    for (int i = 0; i < 16; i++) a += __shfl(g1j, i, 16) * wg2[i];
    const float esuj = sigmf(a) * co;

    esu_o[(size_t)e*16 + j] = esuj;                 // f32-exact stash
    st1<F32>(es_out, (size_t)e*16 + j, esj + esuj); // edge_s residual

    // vc columns (T/E/R) for this feature
    float vT = bT, vE = bE, vR = bR;
    #pragma unroll
    for (int i = 0; i < 16; i++){
        float x = __shfl(esuj, i, 16);
        vT += x * wT[i];
        vE += x * wE[i];
        vR += x * wR[i];
    }

    #pragma unroll
    for (int v = 0; v < 3; v++){
        const float evj = ld1<F32>(edge_v, (size_t)e*48 + v*16 + j);
        const float nvj = nv[(size_t)s*48 + v*16 + j];
        const float vn  = ld1<F32>(vctr, (size_t)e*3 + v);
        const float u = (evj*vT + nvj*vE + vn*vR) * co;
        st1<F32>(ev_out, (size_t)e*48 + v*16 + j, evj + u);
        if (evu_o) evu_o[(size_t)e*48 + v*16 + j] = u;   // f32-exact stash
    }
}

// ---------------- Kernel 3: CSR gather + node output + norms ---------------
// If evu != nullptr: trivial gather (1 load + 1 add per lane per edge, x4
// unrolled). Else: fall back to recompute path (proven, for small ws).
template<bool F32>
__global__ __launch_bounds__(256) void k_node_post(
    const int* __restrict__ mode,
    const void* __restrict__ node_s, const void* __restrict__ node_v,
    const float* __restrict__ esu_ws, const float* __restrict__ evu,
    const float* __restrict__ nvn, const float* __restrict__ nv,
    const void* __restrict__ edge_v, const void* __restrict__ dist, const void* __restrict__ vctr,
    const int* __restrict__ src,
    const int* __restrict__ off, const int* __restrict__ eidx,
    const void* __restrict__ Wtv, const void* __restrict__ btv,
    const void* __restrict__ Wonv, const void* __restrict__ Wo1, const void* __restrict__ bo1,
    const void* __restrict__ Wo2, const void* __restrict__ bo2,
    const void* __restrict__ ln_g, const void* __restrict__ ln_b, const void* __restrict__ cn,
    void* __restrict__ s_out, void* __restrict__ v_out)
{
    if ((mode[0] != 0) != F32) return;
    __shared__ float sWonv[16*128], sWo2[16*128], sWo1[32*16];
    __shared__ float sbo1[16], sbo2[128], slg[128], slb[128], scn[128];
    __shared__ float smess[4][32], sev[4][48], sh[4][16];
    const int tid = threadIdx.x;
    for (int i = tid; i < 2048; i += 256){
        sWonv[i] = ld1<F32>(Wonv, i);
        sWo2[i]  = ld1<F32>(Wo2, i);
    }
    for (int i = tid; i < 512; i += 256) sWo1[i] = ld1<F32>(Wo1, i);
    if (tid < 16) sbo1[tid] = ld1<F32>(bo1, tid);
    if (tid < 128){
        sbo2[tid] = ld1<F32>(bo2, tid);
        slg[tid]  = ld1<F32>(ln_g, tid);
        slb[tid]  = ld1<F32>(ln_b, tid);
        scn[tid]  = ld1<F32>(cn, tid);
    }

    const int w = tid >> 6, lane = tid & 63;
    const int n = blockIdx.x * 4 + w;        // NN = 12500*4
    const int j = lane & 15;
    const int vv = (lane >> 4) - 1;          // 0..2 for lanes >= 16
    const int c48 = lane - 16;               // v*16+j for lanes >= 16

    const int beg = off[n], end = off[n+1];
    float acc = 0.f;

    if (evu){
        // -------- fast path: pre-computed per-edge updates, 1 ld/lane/edge
        const float* gp; int mul, offl;
        if (lane < 16){ gp = esu_ws; mul = 16; offl = j; }
        else          { gp = evu;    mul = 48; offl = c48; }
        int t = beg;
        for (; t + 3 < end; t += 4){
            const int e0 = eidx[t],   e1 = eidx[t+1];
            const int e2 = eidx[t+2], e3 = eidx[t+3];
            const float a0 = gp[(size_t)e0*mul + offl];
            const float a1 = gp[(size_t)e1*mul + offl];
            const float a2 = gp[(size_t)e2*mul + offl];
            const float a3 = gp[(size_t)e3*mul + offl];
            acc += (a0 + a1) + (a2 + a3);
        }
        for (; t < end; ++t)
            acc += gp[(size_t)eidx[t]*mul + offl];
    } else {
        // -------- fallback: recompute vc from esu (small-workspace path)
        float wT[16], wE[16], wR[16];
        #pragma unroll
        for (int i = 0; i < 16; i++){
            wT[i] = ld1<F32>(Wtv, i*48 + j);
            wE[i] = ld1<F32>(Wtv, i*48 + 16 + j);
            wR[i] = ld1<F32>(Wtv, i*48 + 32 + j);
        }
        const float bT = ld1<F32>(btv, j);
        const float bE = ld1<F32>(btv, 16 + j);
        const float bR = ld1<F32>(btv, 32 + j);
        for (int t = beg; t < end; t++){
            const int e = eidx[t];
            float eu[16];
            {
                const float4* ep = reinterpret_cast<const float4*>(esu_ws + (size_t)e*16);
                float4 q0 = ep[0], q1 = ep[1], q2 = ep[2], q3 = ep[3];
                eu[0]=q0.x;  eu[1]=q0.y;  eu[2]=q0.z;  eu[3]=q0.w;
                eu[4]=q1.x;  eu[5]=q1.y;  eu[6]=q1.z;  eu[7]=q1.w;
                eu[8]=q2.x;  eu[9]=q2.y;  eu[10]=q2.z; eu[11]=q2.w;
                eu[12]=q3.x; eu[13]=q3.y; eu[14]=q3.z; eu[15]=q3.w;
            }
            if (lane < 16){
                acc += eu[j];
            } else {
                float tc = bT, ec = bE, rc = bR;
                #pragma unroll
                for (int i = 0; i < 16; i++){
                    tc += eu[i] * wT[i];
                    ec += eu[i] * wE[i];
                    rc += eu[i] * wR[i];
                }
                const float dd = ld1<F32>(dist, e);
                const float co = (dd < 10.f) ? 0.5f * (cosf(dd * 0.3141592653589793f) + 1.f) : 0.f;
                const int se = src[e];
                const float ev  = ld1<F32>(edge_v, (size_t)e*48 + c48);
                const float nvq = nv[(size_t)se*48 + c48];
                const float vn  = ld1<F32>(vctr, (size_t)e*3 + vv);
                acc += (ev*tc + nvq*ec + vn*rc) * co;
            }
        }
    }

    if (lane < 16){
        smess[w][lane]      = acc;                          // n_es
        smess[w][16 + lane] = nvn[(size_t)n*16 + lane];     // nv_norm
    } else {
        sev[w][c48] = acc;                                  // n_ev
    }
    __syncthreads();

    if (lane < 16){
        float a = sbo1[lane];
        #pragma unroll
        for (int i = 0; i < 32; i++) a += smess[w][i] * sWo1[i*16 + lane];
        sh[w][lane] = siluf(a);
    }
    __syncthreads();

    const int g0 = lane * 2;
    float s0, s1;
    {
        float r0, r1;
        ld2v<F32>(node_s, (size_t)n*128 + g0, r0, r1);
        float a0 = sbo2[g0], a1 = sbo2[g0+1];
        #pragma unroll
        for (int i = 0; i < 16; i++){
            float h = sh[w][i];
            a0 += h * sWo2[i*128 + g0];
            a1 += h * sWo2[i*128 + g0 + 1];
        }
        s0 = r0 + a0;
        s1 = r1 + a1;
    }
    float ssum = s0 + s1, ssq = s0*s0 + s1*s1;
    #pragma unroll
    for (int offd = 32; offd >= 1; offd >>= 1){
        ssum += __shfl_xor(ssum, offd, 64);
        ssq  += __shfl_xor(ssq,  offd, 64);
    }
    const float mean = ssum * (1.f/128.f);
    const float var  = ssq * (1.f/128.f) - mean*mean;
    const float rstd = rsqrtf(var + 1e-5f);
    {
        float o0 = (s0 - mean) * rstd * slg[g0]   + slb[g0];
        float o1 = (s1 - mean) * rstd * slg[g0+1] + slb[g0+1];
        st2v<F32>(s_out, (size_t)n*128 + g0, o0, o1);
    }
    float va[3], vb[3];
    #pragma unroll
    for (int v = 0; v < 3; v++){
        float r0, r1;
        ld2v<F32>(node_v, (size_t)n*384 + v*128 + g0, r0, r1);
        float a0 = 0.f, a1 = 0.f;
        #pragma unroll
        for (int i = 0; i < 16; i++){
            float x = sev[w][v*16 + i];
            a0 += x * sWonv[i*128 + g0];
            a1 += x * sWonv[i*128 + g0 + 1];
        }
        va[v] = r0 + a0;
        vb[v] = r1 + a1;
    }
    float n0 = fmaxf(sqrtf(va[0]*va[0] + va[1]*va[1] + va[2]*va[2]), 1e-8f);
    float n1 = fmaxf(sqrtf(vb[0]*vb[0] + vb[1]*vb[1] + vb[2]*vb[2]), 1e-8f);
    const float sc0 = scn[g0]   / n0;
    const float sc1 = scn[g0+1] / n1;
    #pragma unroll
    for (int v = 0; v < 3; v++){
        st2v<F32>(v_out, (size_t)n*384 + v*128 + g0, va[v]*sc0, vb[v]*sc1);
    }
}

extern "C" void kernel_launch(void* const* d_in, const int* in_sizes, int n_in,
                              void* d_out, int out_size, void* d_ws, size_t ws_size,
                              hipStream_t stream)
{
    (void)in_sizes; (void)n_in; (void)out_size;
    const void* node_s = d_in[0];
    const void* node_v = d_in[1];
    const void* edge_s = d_in[2];
    const void* edge_v = d_in[3];
    const void* dist   = d_in[4];
    const void* vctr   = d_in[5];
    const int*  src    = (const int*)d_in[6];
    const int*  dst    = (const int*)d_in[7];
    const void* Wns = d_in[8];  const void* bns = d_in[9];
    const void* Wnv = d_in[10];
    const void* Wen = d_in[11]; const void* ben = d_in[12];
    const void* Wtp = d_in[13]; const void* btp = d_in[14];
    const void* Wg1 = d_in[15]; const void* bg1 = d_in[16];
    const void* Wg2 = d_in[17]; const void* bg2 = d_in[18];
    const void* Wtv = d_in[19]; const void* btv = d_in[20];
    const void* Wonv= d_in[21];
    const void* Wo1 = d_in[22]; const void* bo1 = d_in[23];
    const void* Wo2 = d_in[24]; const void* bo2 = d_in[25];
    const void* lng = d_in[26]; const void* lnb = d_in[27];
    const void* cn  = d_in[28];

    float* ws    = (float*)d_ws;
    float* preS_ = ws;                          // NN*16
    float* preD_ = preS_ + (size_t)NN*16;       // NN*16
    float* nv_   = preD_ + (size_t)NN*16;       // NN*48
    float* nvn_  = nv_   + (size_t)NN*48;       // NN*16
    float* esu_  = nvn_  + (size_t)NN*16;       // EE*16  (51.2 MB)
    int*   off_  = (int*)(esu_ + (size_t)EE*16);// NN+1
    int*   cur_  = off_ + (NN + 1);             // NN  (counts, then cursor)
    int*   eidx_ = cur_ + NN;                   // EE
    int*   flag  = eidx_ + EE;

    // optional evu stash (EE*48 f32 = 153.6 MB) if workspace permits
    size_t used    = (size_t)((char*)(flag + 1) - (char*)d_ws);
    size_t aligned = (used + 255) & ~(size_t)255;
    float* evu_    = (float*)((char*)d_ws + aligned);
    const bool big = ws_size >= aligned + (size_t)EE*48*sizeof(float);
    float* evu_arg = big ? evu_ : nullptr;

    // output layout: same element offsets for either dtype
    char* ob = (char*)d_out;
    const size_t esz_f32 = 4, esz_b16 = 2;
    const size_t off_v  = (size_t)NN*GG;
    const size_t off_es = off_v + (size_t)NN*3*GG;
    const size_t off_ev = off_es + (size_t)EE*LGD;

    hipMemsetAsync(cur_, 0, (size_t)NN*sizeof(int), stream);
    k_detect<<<1, 1024, 0, stream>>>((const u32*)node_s, flag);

    // CSR by dst (dtype-independent)
    k_hist<<<EE/256, 256, 0, stream>>>(dst, cur_);
    k_scan<<<1, 256, 0, stream>>>(cur_, off_);
    k_fill<<<EE/256, 256, 0, stream>>>(dst, cur_, eidx_);

    // bf16-mode pointer bases
    void* s_out_b  = ob;
    void* v_out_b  = ob + off_v  * esz_b16;
    void* es_out_b = ob + off_es * esz_b16;
    void* ev_out_b = ob + off_ev * esz_b16;
    // f32-mode pointer bases
    void* s_out_f  = ob;
    void* v_out_f  = ob + off_v  * esz_f32;
    void* es_out_f = ob + off_es * esz_f32;
    void* ev_out_f = ob + off_ev * esz_f32;

    k_node_pre<false><<<NN/4, 256, 0, stream>>>(flag, node_s, node_v, Wns, bns, Wnv, Wen,
        preS_, preD_, nv_, nvn_);
    k_node_pre<true ><<<NN/4, 256, 0, stream>>>(flag, node_s, node_v, Wns, bns, Wnv, Wen,
        preS_, preD_, nv_, nvn_);

    // feature-parallel fused edge kernel: EE*16 threads
    k_edge<false><<<EE/16, 256, 0, stream>>>(flag, edge_s, edge_v, dist, vctr, src, dst,
        ben, Wtp, btp, Wg1, bg1, Wg2, bg2, Wtv, btv,
        preS_, preD_, nv_, esu_, evu_arg, es_out_b, ev_out_b);
    k_edge<true ><<<EE/16, 256, 0, stream>>>(flag, edge_s, edge_v, dist, vctr, src, dst,
        ben, Wtp, btp, Wg1, bg1, Wg2, bg2, Wtv, btv,
        preS_, preD_, nv_, esu_, evu_arg, es_out_f, ev_out_f);

    k_node_post<false><<<NN/4, 256, 0, stream>>>(flag, node_s, node_v, esu_, evu_arg, nvn_, nv_,
        edge_v, dist, vctr, src, off_, eidx_, Wtv, btv,
        Wonv, Wo1, bo1, Wo2, bo2, lng, lnb, cn, s_out_b, v_out_b);
    k_node_post<true ><<<NN/4, 256, 0, stream>>>(flag, node_s, node_v, esu_, evu_arg, nvn_, nv_,
        edge_v, dist, vctr, src, off_, eidx_, Wtv, btv,
        Wonv, Wo1, bo1, Wo2, bo2, lng, lnb, cn, s_out_f, v_out_f);
}